// Round 11
// baseline (211.954 us; speedup 1.0000x reference)
//
#include <hip/hip_runtime.h>
#include <hip/hip_bf16.h>

// Detect head: prep (fp32->bf16 convert + x transpose) then fused MFMA GEMM + decode.
// R11: barrier-free K-loop.
//   - B (anchor W-tile, 96 rows x C) staged into LDS ONCE per block via
//     global_load_lds (lvl1: two half-K stages of 48KB). Pitch-512B XOR swizzle
//     (pre-swizzled source + swizzled ds_read).
//   - A fragments loaded DIRECTLY global->registers (16B/lane, L2/L3-resident,
//     register-dependency waitcnt, no barriers, no LDS round-trip).
//   - K-loop: ds_read 3 B-frags + 3 MFMA per 32-K step, zero barriers.
//   - Epilogue: decode -> 22KB LDS image (reuses B region) -> contiguous nt float4.
//   - Anchor-major XCD swizzle: each XCD keeps 2-3 B-tiles L2-hot; output spans
//     of consecutive blocks adjacent.

typedef __attribute__((ext_vector_type(8))) short short8;
typedef __attribute__((ext_vector_type(4))) short short4v;
typedef __attribute__((ext_vector_type(4))) float f32x4;
typedef unsigned int u32;

__device__ __forceinline__ unsigned short f2bf(float f) {
    union { float f; unsigned u; } c; c.f = f;
    return (unsigned short)((c.u + 0x7fffu + ((c.u >> 16) & 1u)) >> 16);  // RTNE
}
__device__ __forceinline__ float sigm(float v) {
    return 1.0f / (1.0f + __expf(-v));
}
__device__ __forceinline__ void gload16(const void* g, void* l) {
    __builtin_amdgcn_global_load_lds(
        (const __attribute__((address_space(1))) u32*)g,
        (__attribute__((address_space(3))) u32*)l, 16, 0, 0);
}

#define OUT_CH 1548
#define NCHN   86
#define BPB    7925760   // per-batch output elements = 92160*86

// ---------------- prep kernels ----------------

__global__ void conv_w_kernel(const float* __restrict__ W0, unsigned short* __restrict__ Wb0,
                              const float* __restrict__ W1, unsigned short* __restrict__ Wb1) {
    int i = blockIdx.x * blockDim.x + threadIdx.x;
    if (i >= 297216) return;
    const float* W = W0;
    unsigned short* Wb = Wb0;
    if (i >= 99072) { W = W1; Wb = Wb1; i -= 99072; }
    const float4 f = ((const float4*)W)[i];
    short4v v;
    v[0] = (short)f2bf(f.x); v[1] = (short)f2bf(f.y);
    v[2] = (short)f2bf(f.z); v[3] = (short)f2bf(f.w);
    ((short4v*)Wb)[i] = v;
}

// x [B][C][GG] fp32 -> Xb [B][GG][C] bf16 (64x64 LDS tile transpose)
__global__ void transpose_x_kernel(const float* __restrict__ X, unsigned short* __restrict__ Xb,
                                   int C, int GG) {
    __shared__ float sT[64][65];
    const int p0 = blockIdx.x * 64;
    const int c0 = blockIdx.y * 64;
    const int b  = blockIdx.z;
    const int tid = threadIdx.x;
    const float* src = X + ((size_t)b * C + c0) * GG + p0;
    const int rc = tid >> 4;
    const int cp = (tid & 15) * 4;
    #pragma unroll
    for (int rr = 0; rr < 4; ++rr) {
        const int c = rc + rr * 16;
        const float4 f = *(const float4*)&src[(size_t)c * GG + cp];
        sT[c][cp + 0] = f.x; sT[c][cp + 1] = f.y;
        sT[c][cp + 2] = f.z; sT[c][cp + 3] = f.w;
    }
    __syncthreads();
    const int p  = tid >> 2;
    const int cg = (tid & 3) * 16;
    unsigned short u[16];
    #pragma unroll
    for (int k = 0; k < 16; ++k) u[k] = f2bf(sT[cg + k][p]);
    unsigned short* dst = Xb + ((size_t)b * GG + p0 + p) * C + c0 + cg;
    *(short8*)dst       = *(const short8*)&u[0];
    *(short8*)(dst + 8) = *(const short8*)&u[8];
}

// ---------------- main GEMM + decode ----------------

__global__ __launch_bounds__(512, 4) void detect_gemm(
    const unsigned short* __restrict__ Xb0, const unsigned short* __restrict__ Xb1,
    const unsigned short* __restrict__ Wb0, const unsigned short* __restrict__ Wb1,
    const float* __restrict__ b0, const float* __restrict__ b1,
    float* __restrict__ out)
{
    // LDS 48KB: B tile [96 rows][256 cols] bf16, pitch 512B, XOR-swizzled.
    // Epilogue reuses first 22KB as flat [64*86] fp32 image.
    __shared__ __attribute__((aligned(128))) char smem[49152];
    float* sOutF = (float*)smem;

    // Anchor-major XCD swizzle: 11520 = 8 * 1440; XCD k gets v in [k*1440,(k+1)*1440)
    // = ~2.25 anchors' worth of consecutive mtiles -> B-tile L2-hot per XCD.
    const int bid = blockIdx.x;
    const int v   = (bid & 7) * 1440 + (bid >> 3);
    const int a   = v / 640;          // anchor 0..17
    const int mt  = v - a * 640;      // mtile 0..639

    const bool lvl1 = (mt >= 512);
    const unsigned short* __restrict__ Xb = lvl1 ? Xb1 : Xb0;
    const unsigned short* __restrict__ Wb = lvl1 ? Wb1 : Wb0;
    const float* __restrict__ biasA = (lvl1 ? b1 : b0) + a * NCHN;
    const int C   = lvl1 ? 512 : 256;
    const int GG  = lvl1 ? 1024 : 4096;
    const int Gsh = lvl1 ? 5 : 6;
    const float sxy     = lvl1 ? 1.1f : 1.2f;
    const float sxy_off = (sxy - 1.0f) * 0.5f;
    const float sf      = lvl1 ? 16.0f : 8.0f;
    const int shp  = a / 6;
    const int angi = a - shp * 6;
    const float aw = lvl1 ? ((shp == 0) ? 30.f : (shp == 1) ? 62.f : 59.f)
                          : ((shp == 0) ? 10.f : (shp == 1) ? 16.f : 33.f);
    const float ah = lvl1 ? ((shp == 0) ? 61.f : (shp == 1) ? 45.f : 119.f)
                          : ((shp == 0) ? 13.f : (shp == 1) ? 30.f : 23.f);
    const float aa = (angi == 0) ? -1.04719755119659775f :
                     (angi == 1) ? -0.52359877559829887f :
                     (angi == 2) ?  0.0f :
                     (angi == 3) ?  0.52359877559829887f :
                     (angi == 4) ?  1.04719755119659775f :
                                    1.57079632679489662f;

    const int tloc = lvl1 ? (mt - 512) : mt;
    const int b  = tloc >> (lvl1 ? 4 : 6);               // tiles/img: 16 / 64
    const int p0 = (tloc & ((lvl1 ? 16 : 64) - 1)) * 64; // pixel offset

    const int tid  = threadIdx.x;
    const int lane = tid & 63;
    const int wid  = tid >> 6;        // 0..7
    const int wm = wid >> 1;          // 0..3 : 16-pixel slice
    const int wn = wid & 1;           // 0..1 : 48-channel half

    f32x4 acc[3];
    #pragma unroll
    for (int j = 0; j < 3; ++j)
        acc[j] = f32x4{0.f, 0.f, 0.f, 0.f};

    // ---- B staging geometry (pitch 512B, 96 rows, 6 issues of 8KB) ----
    // issue s: LDS bytes [s*8192 + wid*1024 + lane*16]; row = off>>9, colb = off&511.
    // row = s*16 + wid*2 + (lane>>5); colb = (lane&31)*16.
    // Source pre-swizzled: col ^ ((row&7)<<4); s*16 doesn't change row&7.
    const int rowB  = wid * 2 + (lane >> 5);
    const int colbB = (lane & 31) * 16;
    const int scolE = (colbB ^ ((rowB & 7) << 4)) >> 1;   // element col in Wb

    const int lr   = lane & 15;
    const int kb16 = (lane >> 4) << 4;   // byte offset of this lane's 8-elem k-group

    auto stageB = [&](int k0) {   // stage Wb[a*86 .. +96][k0 .. k0+256] -> 48KB LDS
        #pragma unroll
        for (int s = 0; s < 6; ++s) {
            int grow = a * NCHN + s * 16 + rowB;
            grow = grow > (OUT_CH - 1) ? (OUT_CH - 1) : grow;
            gload16(Wb + (size_t)grow * C + k0 + scolE, smem + s * 8192 + wid * 1024);
        }
    };

    // A fragment base for this lane (byte address into Xb)
    const char* Ap = (const char*)(Xb + ((size_t)b * GG + p0 + wm * 16 + lr) * C) + kb16;

    // one 256-K half: A direct loads + single B stage + barrier-free MFMA loop
    auto halfK = [&](int k0) {
        short8 a8[8];
        #pragma unroll
        for (int kk = 0; kk < 8; ++kk)
            a8[kk] = *(const short8*)(Ap + k0 * 2 + kk * 64);
        stageB(k0);
        __syncthreads();   // single drain: B complete (a8 loads also landed)
        #pragma unroll
        for (int kk = 0; kk < 8; ++kk) {
            const int cb = kk * 64 + kb16;
            short8 bfr[3];
            #pragma unroll
            for (int j = 0; j < 3; ++j) {
                const int rb = wn * 48 + j * 16 + lr;
                bfr[j] = *(const short8*)(smem + rb * 512 + (cb ^ ((rb & 7) << 4)));
            }
            #pragma unroll
            for (int j = 0; j < 3; ++j)
                acc[j] = __builtin_amdgcn_mfma_f32_16x16x32_bf16(a8[kk], bfr[j], acc[j], 0, 0, 0);
        }
    };

    halfK(0);
    if (lvl1) {
        __syncthreads();   // all waves done reading B half 1 before restage
        halfK(256);
    }
    __syncthreads();       // all B reads done before LDS reuse as sOutF

    // ---- epilogue: decode into flat LDS image [64 px][86 ch], then stream out ----
    // C/D layout: col(N)=lane&15, row(M)=(lane>>4)*4+reg
    const int rq = (lane >> 4) * 4;
    const int lvloff = lvl1 ? 73728 : 0;

    #pragma unroll
    for (int j = 0; j < 3; ++j) {
        const int ch = wn * 48 + j * 16 + lr;
        if (ch < NCHN) {
            const float bv = biasA[ch];
            #pragma unroll
            for (int r = 0; r < 4; ++r) {
                const int px = wm * 16 + rq + r;            // 0..63
                const int p  = p0 + px;                     // pixel in level grid
                const float vv = acc[j][r] + bv;
                float res;
                if (ch == 0)      res = (sigm(vv) * sxy - sxy_off + (float)(p & ((1 << Gsh) - 1))) * sf;
                else if (ch == 1) res = (sigm(vv) * sxy - sxy_off + (float)(p >> Gsh)) * sf;
                else if (ch == 2) res = __expf(vv) * aw;
                else if (ch == 3) res = __expf(vv) * ah;
                else if (ch == 4) res = vv + aa;
                else              res = sigm(vv);
                sOutF[px * NCHN + ch] = res;
            }
        }
    }
    __syncthreads();

    // stream out: block span = 64*86 = 5504 dwords, contiguous & 16B-aligned.
    // Non-temporal: write-once data, bypass L2 allocation.
    const size_t spanDw = (size_t)b * BPB + ((size_t)(lvloff + a * GG + p0)) * NCHN;
    #pragma unroll
    for (int k = 0; k < 3; ++k) {
        const int f4 = tid + k * 512;       // float4 index, 1376 total
        if (f4 < 1376) {
            const f32x4 vv = *(const f32x4*)&sOutF[f4 * 4];
            __builtin_nontemporal_store(vv, (f32x4*)&out[spanDw + f4 * 4]);
        }
    }
}

extern "C" void kernel_launch(void* const* d_in, const int* in_sizes, int n_in,
                              void* d_out, int out_size, void* d_ws, size_t ws_size,
                              hipStream_t stream) {
    const float* x0 = (const float*)d_in[0];
    const float* x1 = (const float*)d_in[1];
    const float* W0 = (const float*)d_in[2];
    const float* b0 = (const float*)d_in[3];
    const float* W1 = (const float*)d_in[4];
    const float* b1 = (const float*)d_in[5];
    float* out = (float*)d_out;

    constexpr size_t XB0_OFF = 0;            // 8*4096*256*2  = 16777216
    constexpr size_t XB1_OFF = 16777216;     // 8*1024*512*2  =  8388608
    constexpr size_t WB0_OFF = 25165824;     // 1548*256*2    =   792576
    constexpr size_t WB1_OFF = 25958400;     // 1548*512*2    =  1585152

    unsigned short* Xb0 = (unsigned short*)((char*)d_ws + XB0_OFF);
    unsigned short* Xb1 = (unsigned short*)((char*)d_ws + XB1_OFF);
    unsigned short* Wb0 = (unsigned short*)((char*)d_ws + WB0_OFF);
    unsigned short* Wb1 = (unsigned short*)((char*)d_ws + WB1_OFF);

    hipLaunchKernelGGL(conv_w_kernel, dim3((297216 + 255) / 256), dim3(256), 0, stream,
                       W0, Wb0, W1, Wb1);
    hipLaunchKernelGGL(transpose_x_kernel, dim3(64, 4, 8), dim3(256), 0, stream,
                       x0, Xb0, 256, 4096);
    hipLaunchKernelGGL(transpose_x_kernel, dim3(16, 8, 8), dim3(256), 0, stream,
                       x1, Xb1, 512, 1024);

    // 18 anchors x 640 mtiles = 11520 blocks (anchor-major per XCD)
    hipLaunchKernelGGL(detect_gemm, dim3(11520), dim3(512), 0, stream,
                       Xb0, Xb1, Wb0, Wb1, b0, b1, out);
}

// Round 12
// 148.607 us; speedup vs baseline: 1.4263x; 1.4263x over previous
//
#include <hip/hip_runtime.h>
#include <hip/hip_bf16.h>

// Detect head: prep (fp32->bf16 convert + x transpose) then fused MFMA GEMM + decode.
// R12 = R8 structure + register tiling (the single change):
//   256-thread blocks, 4 waves (2m x 2n), per-wave 32px x 48ch, acc[2][3].
//   Per kk: 5 ds_read_b128 feed 6 MFMAs (19.7 FLOP/LDS-byte vs R8's 8) —
//   attacks the measured LDS-read roofline of the R8 core (~62us of ~83us).
//   Everything else identical to R8: BM=64 x BN=96 anchor tile, BK=64 dbuf +
//   2-phase prefetch, gload_lds w/ XOR swizzle, mtile-major XCD swizzle,
//   LDS-image epilogue + nt float4 stores.

typedef __attribute__((ext_vector_type(8))) short short8;
typedef __attribute__((ext_vector_type(4))) short short4v;
typedef __attribute__((ext_vector_type(4))) float f32x4;
typedef unsigned int u32;

__device__ __forceinline__ unsigned short f2bf(float f) {
    union { float f; unsigned u; } c; c.f = f;
    return (unsigned short)((c.u + 0x7fffu + ((c.u >> 16) & 1u)) >> 16);  // RTNE
}
__device__ __forceinline__ float sigm(float v) {
    return 1.0f / (1.0f + __expf(-v));
}
__device__ __forceinline__ void gload16(const void* g, void* l) {
    __builtin_amdgcn_global_load_lds(
        (const __attribute__((address_space(1))) u32*)g,
        (__attribute__((address_space(3))) u32*)l, 16, 0, 0);
}

#define OUT_CH 1548
#define NCHN   86
#define BPB    7925760   // per-batch output elements = 92160*86

// ---------------- prep kernels ----------------

__global__ void conv_w_kernel(const float* __restrict__ W0, unsigned short* __restrict__ Wb0,
                              const float* __restrict__ W1, unsigned short* __restrict__ Wb1) {
    int i = blockIdx.x * blockDim.x + threadIdx.x;
    if (i >= 297216) return;
    const float* W = W0;
    unsigned short* Wb = Wb0;
    if (i >= 99072) { W = W1; Wb = Wb1; i -= 99072; }
    const float4 f = ((const float4*)W)[i];
    short4v v;
    v[0] = (short)f2bf(f.x); v[1] = (short)f2bf(f.y);
    v[2] = (short)f2bf(f.z); v[3] = (short)f2bf(f.w);
    ((short4v*)Wb)[i] = v;
}

// x [B][C][GG] fp32 -> Xb [B][GG][C] bf16 (64x64 LDS tile transpose)
__global__ void transpose_x_kernel(const float* __restrict__ X, unsigned short* __restrict__ Xb,
                                   int C, int GG) {
    __shared__ float sT[64][65];
    const int p0 = blockIdx.x * 64;
    const int c0 = blockIdx.y * 64;
    const int b  = blockIdx.z;
    const int tid = threadIdx.x;
    const float* src = X + ((size_t)b * C + c0) * GG + p0;
    const int rc = tid >> 4;
    const int cp = (tid & 15) * 4;
    #pragma unroll
    for (int rr = 0; rr < 4; ++rr) {
        const int c = rc + rr * 16;
        const float4 f = *(const float4*)&src[(size_t)c * GG + cp];
        sT[c][cp + 0] = f.x; sT[c][cp + 1] = f.y;
        sT[c][cp + 2] = f.z; sT[c][cp + 3] = f.w;
    }
    __syncthreads();
    const int p  = tid >> 2;
    const int cg = (tid & 3) * 16;
    unsigned short u[16];
    #pragma unroll
    for (int k = 0; k < 16; ++k) u[k] = f2bf(sT[cg + k][p]);
    unsigned short* dst = Xb + ((size_t)b * GG + p0 + p) * C + c0 + cg;
    *(short8*)dst       = *(const short8*)&u[0];
    *(short8*)(dst + 8) = *(const short8*)&u[8];
}

// ---------------- main GEMM + decode ----------------

__global__ __launch_bounds__(256, 4) void detect_gemm(
    const unsigned short* __restrict__ Xb0, const unsigned short* __restrict__ Xb1,
    const unsigned short* __restrict__ Wb0, const unsigned short* __restrict__ Wb1,
    const float* __restrict__ b0, const float* __restrict__ b1,
    float* __restrict__ out)
{
    // LDS 40KB: sA dbuf 2x8KB + sB dbuf 2x12KB; epilogue reuses as flat
    // [64*86] fp32 image (22KB). 4 blocks/CU.
    __shared__ __attribute__((aligned(128))) char smem[40960];
    unsigned short* sAbase = (unsigned short*)smem;               // 2 x 4096 elems
    unsigned short* sBbase = (unsigned short*)(smem + 16384);     // 2 x 6144 elems
    float* sOutF = (float*)smem;

    // XCD swizzle (R8's, mtile-major): 11520 = 8 * 1440; consecutive v within
    // an XCD share the same mtile across 18 anchors -> A-tile L2-hit 17x.
    const int bid = blockIdx.x;
    const int v   = (bid & 7) * 1440 + (bid >> 3);
    const int mt  = v / 18;           // mtile 0..639
    const int a   = v - mt * 18;      // anchor 0..17

    const bool lvl1 = (mt >= 512);
    const unsigned short* __restrict__ Xb = lvl1 ? Xb1 : Xb0;
    const unsigned short* __restrict__ Wb = lvl1 ? Wb1 : Wb0;
    const float* __restrict__ biasA = (lvl1 ? b1 : b0) + a * NCHN;
    const int C   = lvl1 ? 512 : 256;
    const int GG  = lvl1 ? 1024 : 4096;
    const int Gsh = lvl1 ? 5 : 6;
    const float sxy     = lvl1 ? 1.1f : 1.2f;
    const float sxy_off = (sxy - 1.0f) * 0.5f;
    const float sf      = lvl1 ? 16.0f : 8.0f;
    const int shp  = a / 6;
    const int angi = a - shp * 6;
    const float aw = lvl1 ? ((shp == 0) ? 30.f : (shp == 1) ? 62.f : 59.f)
                          : ((shp == 0) ? 10.f : (shp == 1) ? 16.f : 33.f);
    const float ah = lvl1 ? ((shp == 0) ? 61.f : (shp == 1) ? 45.f : 119.f)
                          : ((shp == 0) ? 13.f : (shp == 1) ? 30.f : 23.f);
    const float aa = (angi == 0) ? -1.04719755119659775f :
                     (angi == 1) ? -0.52359877559829887f :
                     (angi == 2) ?  0.0f :
                     (angi == 3) ?  0.52359877559829887f :
                     (angi == 4) ?  1.04719755119659775f :
                                    1.57079632679489662f;

    const int tloc = lvl1 ? (mt - 512) : mt;
    const int b  = tloc >> (lvl1 ? 4 : 6);               // tiles/img: 16 / 64
    const int p0 = (tloc & ((lvl1 ? 16 : 64) - 1)) * 64; // pixel offset

    const unsigned short* __restrict__ Xp = Xb + ((size_t)b * GG + p0) * C;

    const int tid  = threadIdx.x;
    const int lane = tid & 63;
    const int wid  = tid >> 6;        // 0..3
    const int wm = wid >> 1;          // 0..1 : 32-pixel slice
    const int wn = wid & 1;           // 0..1 : 48-channel half

    f32x4 acc[2][3];
    #pragma unroll
    for (int i = 0; i < 2; ++i)
        #pragma unroll
        for (int j = 0; j < 3; ++j)
            acc[i][j] = f32x4{0.f, 0.f, 0.f, 0.f};

    // staging geometry: chunk c covers 8 rows (1KB, 128B row pitch); lane
    // covers base + lane*16 (HW rule). Source col pre-swizzled so the linear
    // LDS image is XOR-swizzled.
    const int rowIn = lane >> 3;                                  // 0..7
    const int scolE = ((((lane & 7) << 4)) ^ (rowIn << 4)) >> 1;  // element col in source

    const int lr   = lane & 15;
    const int kqb  = (lane >> 4) << 4;        // k-quarter byte offset in 64B half-row
    const int swzR = (lr & 7) << 4;           // read-side XOR

    const int KT = C >> 6;

    auto stage = [&](int bufsel, int kt) {
        const int k0 = kt << 6;
        unsigned short* sA = sAbase + bufsel * 4096;
        unsigned short* sB = sBbase + bufsel * 6144;
        // A: 8KB = 2 issues x 4KB (chunks c = i*4+wid, rows c*8+rowIn = 0..63)
        #pragma unroll
        for (int i = 0; i < 2; ++i) {
            const int c = i * 4 + wid;
            const int row = c * 8 + rowIn;
            gload16(Xp + (size_t)row * C + k0 + scolE, (char*)sA + (c << 10));
        }
        // B: 12KB = 3 issues x 4KB (chunks c = j*4+wid, rows 0..95 exactly)
        #pragma unroll
        for (int j = 0; j < 3; ++j) {
            const int c = j * 4 + wid;
            const int row = c * 8 + rowIn;
            int grow = a * NCHN + row;
            grow = grow > (OUT_CH - 1) ? (OUT_CH - 1) : grow;
            gload16(Wb + (size_t)grow * C + k0 + scolE, (char*)sB + (c << 10));
        }
    };

    auto compute = [&](int bufsel) {
        const char* sA = (const char*)(sAbase + bufsel * 4096);
        const char* sB = (const char*)(sBbase + bufsel * 6144);
        #pragma unroll
        for (int kk = 0; kk < 2; ++kk) {
            const int cb = (kk << 6) + kqb;
            short8 af[2], bfr[3];
            #pragma unroll
            for (int i = 0; i < 2; ++i) {
                const int ra = wm * 32 + i * 16 + lr;
                af[i] = *(const short8*)(sA + ra * 128 + (cb ^ swzR));
            }
            #pragma unroll
            for (int j = 0; j < 3; ++j) {
                const int rb = wn * 48 + j * 16 + lr;
                bfr[j] = *(const short8*)(sB + rb * 128 + (cb ^ swzR));
            }
            #pragma unroll
            for (int i = 0; i < 2; ++i)
                #pragma unroll
                for (int j = 0; j < 3; ++j)
                    acc[i][j] = __builtin_amdgcn_mfma_f32_16x16x32_bf16(af[i], bfr[j], acc[i][j], 0, 0, 0);
        }
    };

    // prologue + 2-phase pipelined K loop (issue next-tile loads BEFORE compute)
    stage(0, 0);
    __syncthreads();
    int cur = 0;
    for (int kt = 0; kt < KT; ++kt) {
        if (kt + 1 < KT) stage(cur ^ 1, kt + 1);
        compute(cur);
        __syncthreads();          // drains this iteration's prefetch loads too
        cur ^= 1;
    }

    // ---- epilogue: decode into flat LDS image [64 px][86 ch], then stream out ----
    // C/D layout: col(N)=lane&15, row(M)=(lane>>4)*4+reg
    const int rq = (lane >> 4) * 4;
    const int lvloff = lvl1 ? 73728 : 0;

    #pragma unroll
    for (int j = 0; j < 3; ++j) {
        const int ch = wn * 48 + j * 16 + lr;
        if (ch < NCHN) {
            const float bv = biasA[ch];
            #pragma unroll
            for (int i = 0; i < 2; ++i) {
                #pragma unroll
                for (int r = 0; r < 4; ++r) {
                    const int px = wm * 32 + i * 16 + rq + r;   // 0..63
                    const int p  = p0 + px;                     // pixel in level grid
                    const float vv = acc[i][j][r] + bv;
                    float res;
                    if (ch == 0)      res = (sigm(vv) * sxy - sxy_off + (float)(p & ((1 << Gsh) - 1))) * sf;
                    else if (ch == 1) res = (sigm(vv) * sxy - sxy_off + (float)(p >> Gsh)) * sf;
                    else if (ch == 2) res = __expf(vv) * aw;
                    else if (ch == 3) res = __expf(vv) * ah;
                    else if (ch == 4) res = vv + aa;
                    else              res = sigm(vv);
                    sOutF[px * NCHN + ch] = res;
                }
            }
        }
    }
    __syncthreads();

    // stream out: block span = 64*86 = 5504 dwords, contiguous & 16B-aligned.
    // Non-temporal: write-once data, bypass L2 allocation.
    const size_t spanDw = (size_t)b * BPB + ((size_t)(lvloff + a * GG + p0)) * NCHN;
    #pragma unroll
    for (int k = 0; k < 6; ++k) {
        const int f4 = tid + k * 256;       // float4 index, 1376 total
        if (f4 < 1376) {
            const f32x4 vv = *(const f32x4*)&sOutF[f4 * 4];
            __builtin_nontemporal_store(vv, (f32x4*)&out[spanDw + f4 * 4]);
        }
    }
}

extern "C" void kernel_launch(void* const* d_in, const int* in_sizes, int n_in,
                              void* d_out, int out_size, void* d_ws, size_t ws_size,
                              hipStream_t stream) {
    const float* x0 = (const float*)d_in[0];
    const float* x1 = (const float*)d_in[1];
    const float* W0 = (const float*)d_in[2];
    const float* b0 = (const float*)d_in[3];
    const float* W1 = (const float*)d_in[4];
    const float* b1 = (const float*)d_in[5];
    float* out = (float*)d_out;

    constexpr size_t XB0_OFF = 0;            // 8*4096*256*2  = 16777216
    constexpr size_t XB1_OFF = 16777216;     // 8*1024*512*2  =  8388608
    constexpr size_t WB0_OFF = 25165824;     // 1548*256*2    =   792576
    constexpr size_t WB1_OFF = 25958400;     // 1548*512*2    =  1585152

    unsigned short* Xb0 = (unsigned short*)((char*)d_ws + XB0_OFF);
    unsigned short* Xb1 = (unsigned short*)((char*)d_ws + XB1_OFF);
    unsigned short* Wb0 = (unsigned short*)((char*)d_ws + WB0_OFF);
    unsigned short* Wb1 = (unsigned short*)((char*)d_ws + WB1_OFF);

    hipLaunchKernelGGL(conv_w_kernel, dim3((297216 + 255) / 256), dim3(256), 0, stream,
                       W0, Wb0, W1, Wb1);
    hipLaunchKernelGGL(transpose_x_kernel, dim3(64, 4, 8), dim3(256), 0, stream,
                       x0, Xb0, 256, 4096);
    hipLaunchKernelGGL(transpose_x_kernel, dim3(16, 8, 8), dim3(256), 0, stream,
                       x1, Xb1, 512, 1024);

    // 640 mtiles (512 lvl0 + 128 lvl1) x 18 anchors = 11520 blocks
    hipLaunchKernelGGL(detect_gemm, dim3(11520), dim3(256), 0, stream,
                       Xb0, Xb1, Wb0, Wb1, b0, b1, out);
}